// Round 2
// baseline (121.009 us; speedup 1.0000x reference)
//
#include <hip/hip_runtime.h>

// P = dW/dF for W(F) = 8*tr(C) + 10*J^2 - 56*log(J) + 0.2*(I4^2 + I5^2) - 44
// C = F^T F, J = det F, G = diag(4, .5, .5), I4 = tr(C G), I5 = tr(cof(C) G)
// Analytic gradient:
//   P = 16 F + [20 J^2 - 56 + 0.8 I5^2] F^-T + 0.8 I4 * F G - 0.8 I5 * F^-T G cofC
// with F^-T = cof(F)/J, cofC = cof(C).
//
// R1: float2 (dwordx2) global access, 2 samples/thread, XOR-swizzled LDS,
//     non-temporal output stores (keep 108 MB input L3-resident across replays).

typedef float f2 __attribute__((ext_vector_type(2)));

#define SAMPLES_PER_BLOCK 512
#define F2_PER_BLOCK (SAMPLES_PER_BLOCK * 9 / 2)   // 2304 float2

__device__ __forceinline__ int swz(int i) { return i ^ ((i >> 4) & 15); }

__global__ __launch_bounds__(256, 8) void pk1_grad_kernel(
    const f2* __restrict__ Fin, f2* __restrict__ Pout, int total2)
{
    __shared__ f2 lds2[F2_PER_BLOCK];
    const int t = threadIdx.x;
    const int base2 = blockIdx.x * F2_PER_BLOCK;

    // ---- coalesced staging: global -> LDS (8B per lane, consecutive) ----
#pragma unroll
    for (int j = 0; j < 9; ++j) {
        int i = j * 256 + t;
        int g = base2 + i;
        f2 v;
        if (g < total2) v = Fin[g];
        else { v.x = 1.0f; v.y = 1.0f; }   // benign pad (results discarded)
        lds2[swz(i)] = v;
    }
    __syncthreads();

    // ---- per-thread: read 2 samples (18 floats) via swizzled b64 reads ----
    float buf[18];
#pragma unroll
    for (int q = 0; q < 9; ++q) {
        f2 v = lds2[swz(t * 9 + q)];
        buf[2 * q]     = v.x;
        buf[2 * q + 1] = v.y;
    }

#pragma unroll
    for (int s = 0; s < 2; ++s) {
        float f[9];
#pragma unroll
        for (int k = 0; k < 9; ++k) f[k] = buf[s * 9 + k];

        // cof(F): F^-T = cof(F)/J
        float c00 = f[4]*f[8] - f[5]*f[7];
        float c01 = f[5]*f[6] - f[3]*f[8];
        float c02 = f[3]*f[7] - f[4]*f[6];
        float c10 = f[2]*f[7] - f[1]*f[8];
        float c11 = f[0]*f[8] - f[2]*f[6];
        float c12 = f[1]*f[6] - f[0]*f[7];
        float c20 = f[1]*f[5] - f[2]*f[4];
        float c21 = f[2]*f[3] - f[0]*f[5];
        float c22 = f[0]*f[4] - f[1]*f[3];
        float J    = f[0]*c00 + f[1]*c01 + f[2]*c02;
        float invJ = 1.0f / J;

        // C = F^T F (symmetric)
        float C00 = f[0]*f[0] + f[3]*f[3] + f[6]*f[6];
        float C11 = f[1]*f[1] + f[4]*f[4] + f[7]*f[7];
        float C22 = f[2]*f[2] + f[5]*f[5] + f[8]*f[8];
        float C01 = f[0]*f[1] + f[3]*f[4] + f[6]*f[7];
        float C02 = f[0]*f[2] + f[3]*f[5] + f[6]*f[8];
        float C12 = f[1]*f[2] + f[4]*f[5] + f[7]*f[8];

        float I4 = 4.0f*C00 + 0.5f*(C11 + C22);

        // cof(C) (symmetric)
        float K00 = C11*C22 - C12*C12;
        float K11 = C00*C22 - C02*C02;
        float K22 = C00*C11 - C01*C01;
        float K01 = C02*C12 - C01*C22;
        float K02 = C01*C12 - C02*C11;
        float K12 = C01*C02 - C00*C12;

        float I5 = 4.0f*K00 + 0.5f*(K11 + K22);

        float J2    = J * J;
        float alpha = (20.0f*J2 - 56.0f + 0.8f*I5*I5) * invJ;  // coeff on cof(F)
        float beta  = 0.8f * I4;                                // coeff on F G
        float gamma = -0.8f * I5 * invJ;                        // coeff on cof(F) G cofC

        float cf[3][3] = {{c00,c01,c02},{c10,c11,c12},{c20,c21,c22}};
        float K[3][3]  = {{K00,K01,K02},{K01,K11,K12},{K02,K12,K22}};
        const float gv[3] = {4.0f, 0.5f, 0.5f};

#pragma unroll
        for (int i = 0; i < 3; ++i) {
            float a0 = cf[i][0] * 4.0f;
            float a1 = cf[i][1] * 0.5f;
            float a2 = cf[i][2] * 0.5f;
#pragma unroll
            for (int j = 0; j < 3; ++j) {
                float M = a0 * K[0][j] + a1 * K[1][j] + a2 * K[2][j];
                buf[s * 9 + 3 * i + j] =
                      (16.0f + beta * gv[j]) * f[3 * i + j]
                    + alpha * cf[i][j]
                    + gamma * M;
            }
        }
    }

    // ---- write results back via swizzled b64 writes ----
#pragma unroll
    for (int q = 0; q < 9; ++q) {
        f2 v;
        v.x = buf[2 * q];
        v.y = buf[2 * q + 1];
        lds2[swz(t * 9 + q)] = v;
    }
    __syncthreads();

    // ---- coalesced non-temporal store: LDS -> global (bypass L3) ----
#pragma unroll
    for (int j = 0; j < 9; ++j) {
        int i = j * 256 + t;
        int g = base2 + i;
        if (g < total2) {
            f2 v = lds2[swz(i)];
            __builtin_nontemporal_store(v, &Pout[g]);
        }
    }
}

extern "C" void kernel_launch(void* const* d_in, const int* in_sizes, int n_in,
                              void* d_out, int out_size, void* d_ws, size_t ws_size,
                              hipStream_t stream) {
    const f2* F = (const f2*)d_in[0];
    f2* P = (f2*)d_out;
    int total2 = in_sizes[0] / 2;             // 13,500,000 float2
    int blocks = (total2 + F2_PER_BLOCK - 1) / F2_PER_BLOCK;
    pk1_grad_kernel<<<blocks, 256, 0, stream>>>(F, P, total2);
}

// Round 3
// 44.936 us; speedup vs baseline: 2.6929x; 2.6929x over previous
//
#include <hip/hip_runtime.h>

// P = dW/dF for W(F) = 8*tr(C) + 10*J^2 - 56*log(J) + 0.2*(I4^2 + I5^2) - 44
// C = F^T F, J = det F, G = diag(4, .5, .5), I4 = tr(C G), I5 = tr(cof(C) G)
// Analytic gradient:
//   P = 16 F + [20 J^2 - 56 + 0.8 I5^2] F^-T + 0.8 I4 * F G - 0.8 I5 * F^-T G cofC
// with F^-T = cof(F)/J, cofC = cof(C).
//
// R2: revert R1's regressions (nt stores -> 4x write amplification; XOR swizzle
//     CREATED the bank conflicts -- stride-9 odd layouts self-spread mod 32).
//     Keep R0 structure, widen global access to float4 (16B/lane), 4 samples/thread.

typedef float f4 __attribute__((ext_vector_type(4)));

#define SAMPLES_PER_BLOCK 1024
#define F4_PER_BLOCK (SAMPLES_PER_BLOCK * 9 / 4)   // 2304 float4 = 36 KB

__global__ __launch_bounds__(256, 4) void pk1_grad_kernel(
    const f4* __restrict__ Fin, f4* __restrict__ Pout, int total4)
{
    __shared__ f4 lds4[F4_PER_BLOCK];
    const int t = threadIdx.x;
    const int base4 = blockIdx.x * F4_PER_BLOCK;

    // ---- coalesced staging: global -> LDS, 16B/lane, consecutive ----
#pragma unroll
    for (int j = 0; j < 9; ++j) {
        int i = j * 256 + t;
        int g = base4 + i;
        f4 v;
        if (g < total4) v = Fin[g];
        else { v.x = 1.0f; v.y = 0.0f; v.z = 0.0f; v.w = 1.0f; } // benign pad
        lds4[i] = v;
    }
    __syncthreads();

    // ---- per-thread: 4 samples = 36 floats = 9 f4, stride-9 reads (2-way, free) ----
    float buf[36];
#pragma unroll
    for (int q = 0; q < 9; ++q) {
        f4 v = lds4[t * 9 + q];
        buf[4 * q]     = v.x;
        buf[4 * q + 1] = v.y;
        buf[4 * q + 2] = v.z;
        buf[4 * q + 3] = v.w;
    }

#pragma unroll
    for (int s = 0; s < 4; ++s) {
        float f[9];
#pragma unroll
        for (int k = 0; k < 9; ++k) f[k] = buf[s * 9 + k];

        // cof(F): F^-T = cof(F)/J
        float c00 = f[4]*f[8] - f[5]*f[7];
        float c01 = f[5]*f[6] - f[3]*f[8];
        float c02 = f[3]*f[7] - f[4]*f[6];
        float c10 = f[2]*f[7] - f[1]*f[8];
        float c11 = f[0]*f[8] - f[2]*f[6];
        float c12 = f[1]*f[6] - f[0]*f[7];
        float c20 = f[1]*f[5] - f[2]*f[4];
        float c21 = f[2]*f[3] - f[0]*f[5];
        float c22 = f[0]*f[4] - f[1]*f[3];
        float J    = f[0]*c00 + f[1]*c01 + f[2]*c02;
        float invJ = 1.0f / J;

        // C = F^T F (symmetric)
        float C00 = f[0]*f[0] + f[3]*f[3] + f[6]*f[6];
        float C11 = f[1]*f[1] + f[4]*f[4] + f[7]*f[7];
        float C22 = f[2]*f[2] + f[5]*f[5] + f[8]*f[8];
        float C01 = f[0]*f[1] + f[3]*f[4] + f[6]*f[7];
        float C02 = f[0]*f[2] + f[3]*f[5] + f[6]*f[8];
        float C12 = f[1]*f[2] + f[4]*f[5] + f[7]*f[8];

        float I4 = 4.0f*C00 + 0.5f*(C11 + C22);

        // cof(C) (symmetric)
        float K00 = C11*C22 - C12*C12;
        float K11 = C00*C22 - C02*C02;
        float K22 = C00*C11 - C01*C01;
        float K01 = C02*C12 - C01*C22;
        float K02 = C01*C12 - C02*C11;
        float K12 = C01*C02 - C00*C12;

        float I5 = 4.0f*K00 + 0.5f*(K11 + K22);

        float J2    = J * J;
        float alpha = (20.0f*J2 - 56.0f + 0.8f*I5*I5) * invJ;  // coeff on cof(F)
        float beta  = 0.8f * I4;                                // coeff on F G
        float gamma = -0.8f * I5 * invJ;                        // coeff on cof(F) G cofC

        float cf[3][3] = {{c00,c01,c02},{c10,c11,c12},{c20,c21,c22}};
        float K[3][3]  = {{K00,K01,K02},{K01,K11,K12},{K02,K12,K22}};
        const float gv[3] = {4.0f, 0.5f, 0.5f};

#pragma unroll
        for (int i = 0; i < 3; ++i) {
            float a0 = cf[i][0] * 4.0f;
            float a1 = cf[i][1] * 0.5f;
            float a2 = cf[i][2] * 0.5f;
#pragma unroll
            for (int j = 0; j < 3; ++j) {
                float M = a0 * K[0][j] + a1 * K[1][j] + a2 * K[2][j];
                buf[s * 9 + 3 * i + j] =
                      (16.0f + beta * gv[j]) * f[3 * i + j]
                    + alpha * cf[i][j]
                    + gamma * M;
            }
        }
    }

    __syncthreads();   // protect LDS reuse (all compute reads done)

    // ---- results back to LDS, then coalesced cached stores ----
#pragma unroll
    for (int q = 0; q < 9; ++q) {
        f4 v;
        v.x = buf[4 * q];
        v.y = buf[4 * q + 1];
        v.z = buf[4 * q + 2];
        v.w = buf[4 * q + 3];
        lds4[t * 9 + q] = v;
    }
    __syncthreads();

#pragma unroll
    for (int j = 0; j < 9; ++j) {
        int i = j * 256 + t;
        int g = base4 + i;
        if (g < total4) Pout[g] = lds4[i];
    }
}

extern "C" void kernel_launch(void* const* d_in, const int* in_sizes, int n_in,
                              void* d_out, int out_size, void* d_ws, size_t ws_size,
                              hipStream_t stream) {
    const f4* F = (const f4*)d_in[0];
    f4* P = (f4*)d_out;
    int total4 = in_sizes[0] / 4;             // 6,750,000 float4
    int blocks = (total4 + F4_PER_BLOCK - 1) / F4_PER_BLOCK;
    pk1_grad_kernel<<<blocks, 256, 0, stream>>>(F, P, total4);
}